// Round 9
// baseline (1817.342 us; speedup 1.0000x reference)
//
#include <hip/hip_runtime.h>
#include <math.h>

// GraphUnet on MI355X.
//  - (A@X)@W+b as A@(X@W)+b; pooled A never materialized.
//  - HYBRID precision: layers start/down0 in fp32 vector (protect level-0
//    top-k ranking: boundary gap ~7e-4 needs fp32-accurate D0); remaining
//    9 heavy layers via 3-term bf16-split MFMA (Ah*Zh + Ah*Zl + Al*Zh,
//    rel err ~2e-5; pool levels 1-3 have saturated/huge logits -> safe).
//  - NO-GATHER MFMA: computes all 8192 rows of A0 @ Zn (+37% flops) so A
//    staging is coalesced/linear; k_reduce applies the row gather.
//  - k_big_mfma: BM=256 x 64, BK=32, 4 waves, 32x32x16 bf16 frags,
//    M_rep=2 x N_rep=2, 3 products into same fp32 acc. A/Z tiles staged
//    via global_load_lds with source-XOR chunk swizzle (slot = c ^ ((r +
//    (r>>2))&3)) -> frag ds_read_b128 conflict-free per 8-lane phase.
//  - top-k via exact rank counting (jax.lax.top_k tie-break).
//  - split-K partials + deterministic fused reduce (bias+resid+gather).

#define N0 8192
#define BM 256
#define BK 32

typedef __attribute__((ext_vector_type(8))) short bf16x8;
typedef __attribute__((ext_vector_type(16))) float f32x16;

#define SLOTOF(R, c) ((c) ^ (((R) + ((R) >> 2)) & 3))

__device__ __forceinline__ unsigned short bf16_rtn(float f) {
    unsigned u = __float_as_uint(f);
    return (unsigned short)((u + 0x7fffu + ((u >> 16) & 1u)) >> 16);
}

// ---------------------------------------------------------------- split A
// Ah/Al bf16 (RTN hi + RTN residual), same row-major layout as A.
__global__ __launch_bounds__(256) void k_split_A(
    const float* __restrict__ A, unsigned short* __restrict__ Ah,
    unsigned short* __restrict__ Al)
{
    const size_t total = (size_t)N0 * N0 / 8;
    for (size_t i = (size_t)blockIdx.x * 256 + threadIdx.x; i < total;
         i += (size_t)gridDim.x * 256) {
        const float* a = A + i * 8;
        float4 f0 = *(const float4*)a;
        float4 f1 = *(const float4*)(a + 4);
        float f[8] = {f0.x, f0.y, f0.z, f0.w, f1.x, f1.y, f1.z, f1.w};
        bf16x8 hv, lv;
#pragma unroll
        for (int j = 0; j < 8; ++j) {
            unsigned short h = bf16_rtn(f[j]);
            hv[j] = (short)h;
            float hf = __uint_as_float(((unsigned)h) << 16);
            lv[j] = (short)bf16_rtn(f[j] - hf);
        }
        *(bf16x8*)(Ah + i * 8) = hv;
        *(bf16x8*)(Al + i * 8) = lv;
    }
}

// ---------------------------------------------------------------- small gemm
// fp32 path: Z[oidx?oidx[r]:r] = X1[r,:]@W1 (+ X2[r,:]@W2)
__global__ __launch_bounds__(256) void k_small_gemm(
    const float* __restrict__ X1, const float* __restrict__ W1,
    const float* __restrict__ X2, const float* __restrict__ W2,
    const int* __restrict__ oidx, float* __restrict__ Z, int rows)
{
    __shared__ __align__(16) float Ws1[64][64];
    __shared__ __align__(16) float Ws2[64][64];
    __shared__ __align__(16) float Xs1[32][64];
    __shared__ __align__(16) float Xs2[32][64];
    const int tid = threadIdx.x;
    const int r0 = blockIdx.x * 32;

#pragma unroll
    for (int l = 0; l < 4; ++l) {
        int idx = tid + 256 * l;
        int rw = idx >> 4, c4 = (idx & 15) * 4;
        *(float4*)&Ws1[rw][c4] = *(const float4*)(W1 + rw * 64 + c4);
    }
    if (X2) {
#pragma unroll
        for (int l = 0; l < 4; ++l) {
            int idx = tid + 256 * l;
            int rw = idx >> 4, c4 = (idx & 15) * 4;
            *(float4*)&Ws2[rw][c4] = *(const float4*)(W2 + rw * 64 + c4);
        }
    }
#pragma unroll
    for (int l = 0; l < 2; ++l) {
        int idx = tid + 256 * l;
        int rl = idx >> 4, c4 = (idx & 15) * 4;
        int r = r0 + rl;
        float4 v = make_float4(0.f, 0.f, 0.f, 0.f);
        if (r < rows) v = *(const float4*)(X1 + (size_t)r * 64 + c4);
        *(float4*)&Xs1[rl][c4] = v;
        if (X2) {
            float4 v2 = make_float4(0.f, 0.f, 0.f, 0.f);
            if (r < rows) v2 = *(const float4*)(X2 + (size_t)r * 64 + c4);
            *(float4*)&Xs2[rl][c4] = v2;
        }
    }
    __syncthreads();

    const int c = tid & 63;
    const int rg = tid >> 6;
    float acc[8] = {0, 0, 0, 0, 0, 0, 0, 0};
#pragma unroll
    for (int k4 = 0; k4 < 16; ++k4) {
        float w0 = Ws1[k4 * 4 + 0][c], w1 = Ws1[k4 * 4 + 1][c];
        float w2 = Ws1[k4 * 4 + 2][c], w3 = Ws1[k4 * 4 + 3][c];
#pragma unroll
        for (int j = 0; j < 8; ++j) {
            float4 x = *(const float4*)&Xs1[rg * 8 + j][k4 * 4];
            acc[j] += x.x * w0 + x.y * w1 + x.z * w2 + x.w * w3;
        }
        if (X2) {
            float u0 = Ws2[k4 * 4 + 0][c], u1 = Ws2[k4 * 4 + 1][c];
            float u2 = Ws2[k4 * 4 + 2][c], u3 = Ws2[k4 * 4 + 3][c];
#pragma unroll
            for (int j = 0; j < 8; ++j) {
                float4 x = *(const float4*)&Xs2[rg * 8 + j][k4 * 4];
                acc[j] += x.x * u0 + x.y * u1 + x.z * u2 + x.w * u3;
            }
        }
    }
#pragma unroll
    for (int j = 0; j < 8; ++j) {
        int r = r0 + rg * 8 + j;
        if (r < rows) {
            int ro = oidx ? oidx[r] : r;
            Z[(size_t)ro * 64 + c] = acc[j];
        }
    }
}

// ------------------------------------------------------- small gemm (bf16 T)
// MFMA path: same math, outputs bf16-split TRANSPOSED Zh^T/Zl^T [64][N0],
// scattered to original row indices.
__global__ __launch_bounds__(256) void k_small_gemm_T(
    const float* __restrict__ X1, const float* __restrict__ W1,
    const float* __restrict__ X2, const float* __restrict__ W2,
    const int* __restrict__ oidx, unsigned short* __restrict__ ZhT,
    unsigned short* __restrict__ ZlT, int rows)
{
    __shared__ __align__(16) float Ws1[64][64];
    __shared__ __align__(16) float Ws2[64][64];
    __shared__ __align__(16) float Xs1[32][64];
    __shared__ __align__(16) float Xs2[32][64];
    const int tid = threadIdx.x;
    const int r0 = blockIdx.x * 32;

#pragma unroll
    for (int l = 0; l < 4; ++l) {
        int idx = tid + 256 * l;
        int rw = idx >> 4, c4 = (idx & 15) * 4;
        *(float4*)&Ws1[rw][c4] = *(const float4*)(W1 + rw * 64 + c4);
    }
    if (X2) {
#pragma unroll
        for (int l = 0; l < 4; ++l) {
            int idx = tid + 256 * l;
            int rw = idx >> 4, c4 = (idx & 15) * 4;
            *(float4*)&Ws2[rw][c4] = *(const float4*)(W2 + rw * 64 + c4);
        }
    }
#pragma unroll
    for (int l = 0; l < 2; ++l) {
        int idx = tid + 256 * l;
        int rl = idx >> 4, c4 = (idx & 15) * 4;
        int r = r0 + rl;
        float4 v = make_float4(0.f, 0.f, 0.f, 0.f);
        if (r < rows) v = *(const float4*)(X1 + (size_t)r * 64 + c4);
        *(float4*)&Xs1[rl][c4] = v;
        if (X2) {
            float4 v2 = make_float4(0.f, 0.f, 0.f, 0.f);
            if (r < rows) v2 = *(const float4*)(X2 + (size_t)r * 64 + c4);
            *(float4*)&Xs2[rl][c4] = v2;
        }
    }
    __syncthreads();

    const int c = tid & 63;
    const int rg = tid >> 6;
    float acc[8] = {0, 0, 0, 0, 0, 0, 0, 0};
#pragma unroll
    for (int k4 = 0; k4 < 16; ++k4) {
        float w0 = Ws1[k4 * 4 + 0][c], w1 = Ws1[k4 * 4 + 1][c];
        float w2 = Ws1[k4 * 4 + 2][c], w3 = Ws1[k4 * 4 + 3][c];
#pragma unroll
        for (int j = 0; j < 8; ++j) {
            float4 x = *(const float4*)&Xs1[rg * 8 + j][k4 * 4];
            acc[j] += x.x * w0 + x.y * w1 + x.z * w2 + x.w * w3;
        }
        if (X2) {
            float u0 = Ws2[k4 * 4 + 0][c], u1 = Ws2[k4 * 4 + 1][c];
            float u2 = Ws2[k4 * 4 + 2][c], u3 = Ws2[k4 * 4 + 3][c];
#pragma unroll
            for (int j = 0; j < 8; ++j) {
                float4 x = *(const float4*)&Xs2[rg * 8 + j][k4 * 4];
                acc[j] += x.x * u0 + x.y * u1 + x.z * u2 + x.w * u3;
            }
        }
    }
#pragma unroll
    for (int j = 0; j < 8; ++j) {
        int r = r0 + rg * 8 + j;
        if (r < rows) {
            int ro = oidx ? oidx[r] : r;
            float z = acc[j];
            unsigned short h = bf16_rtn(z);
            float hf = __uint_as_float(((unsigned)h) << 16);
            unsigned short lo = bf16_rtn(z - hf);
            ZhT[(size_t)c * N0 + ro] = h;
            ZlT[(size_t)c * N0 + ro] = lo;
        }
    }
}

// ----------------------------------------------------------- big gemm fp32
__global__ __launch_bounds__(256) void k_big_gemm(
    const float* __restrict__ A, const float* __restrict__ Zn,
    const int* __restrict__ gidx, float* __restrict__ P,
    int rows, int kchunk)
{
    __shared__ __align__(16) float As[BM * BK];
    __shared__ __align__(16) float Zs[BK * 64];
    const int tid = threadIdx.x;
    const int w = tid >> 6, l = tid & 63;
    const int tx = tid & 7;
    const int ty = tid >> 3;
    const int r0 = blockIdx.x * BM;
    const int k0 = blockIdx.y * kchunk;
    const int ntiles = kchunk / BK;

    unsigned goff[8];
#pragma unroll
    for (int j = 0; j < 8; ++j) {
        int R = j * 32 + w * 8 + (l >> 3);
        int r = r0 + R;
        int rr = (r < rows) ? r : rows - 1;
        int g = gidx ? gidx[rr] : rr;
        int sw = (j * 4 + w) & 7;
        goff[j] = (unsigned)g * (unsigned)(N0 * 4) +
                  (unsigned)(k0 + (((l & 7) ^ sw) << 2)) * 4u;
    }

    float acc[8][8];
#pragma unroll
    for (int i = 0; i < 8; ++i)
#pragma unroll
        for (int j = 0; j < 8; ++j) acc[i][j] = 0.f;

    for (int t = 0; t < ntiles; ++t) {
        const unsigned ktb = (unsigned)(t * BK) * 4u;
#pragma unroll
        for (int j = 0; j < 8; ++j)
            __builtin_amdgcn_global_load_lds(
                (const __attribute__((address_space(1))) void*)
                    ((const char*)A + (goff[j] + ktb)),
                (__attribute__((address_space(3))) void*)
                    (&As[j * 1024 + w * 256]),
                16, 0, 0);
        {
            const float* zsrc = Zn + (size_t)(k0 + t * BK) * 64;
#pragma unroll
            for (int q = 0; q < 2; ++q)
                __builtin_amdgcn_global_load_lds(
                    (const __attribute__((address_space(1))) void*)
                        (zsrc + (w * 2 + q) * 256 + l * 4),
                    (__attribute__((address_space(3))) void*)
                        (&Zs[(w * 2 + q) * 256]),
                    16, 0, 0);
        }
        __syncthreads();

#pragma unroll
        for (int k4 = 0; k4 < 8; ++k4) {
            float4 af[8];
            const int slot = ((k4 ^ (ty & 7)) << 2);
#pragma unroll
            for (int i = 0; i < 8; ++i)
                af[i] = *(const float4*)&As[(ty * 8 + i) * 32 + slot];
#pragma unroll
            for (int q = 0; q < 4; ++q) {
                const int kk = k4 * 4 + q;
                float4 z0 = *(const float4*)&Zs[kk * 64 + tx * 8];
                float4 z1 = *(const float4*)&Zs[kk * 64 + tx * 8 + 4];
                float zb[8] = {z0.x, z0.y, z0.z, z0.w,
                               z1.x, z1.y, z1.z, z1.w};
#pragma unroll
                for (int i = 0; i < 8; ++i) {
                    const float a = (q == 0) ? af[i].x : (q == 1) ? af[i].y
                                   : (q == 2) ? af[i].z : af[i].w;
#pragma unroll
                    for (int j = 0; j < 8; ++j) acc[i][j] += a * zb[j];
                }
            }
        }
        __syncthreads();
    }

    float* Pp = P + (size_t)blockIdx.y * rows * 64;
#pragma unroll
    for (int i = 0; i < 8; ++i) {
        int r = r0 + ty * 8 + i;
        if (r < rows) {
            float4 v0 = make_float4(acc[i][0], acc[i][1], acc[i][2], acc[i][3]);
            float4 v1 = make_float4(acc[i][4], acc[i][5], acc[i][6], acc[i][7]);
            *(float4*)(Pp + (size_t)r * 64 + tx * 8) = v0;
            *(float4*)(Pp + (size_t)r * 64 + tx * 8 + 4) = v1;
        }
    }
}

// ----------------------------------------------------------- big gemm MFMA
// P[sp][i][c] = sum_k A0[i,k]*Zn[k,c] for ALL i in 0..8192 (no gather).
// 3-term bf16 split. 4 waves; wave w owns rows w*64..w*64+64 (M_rep=2 of
// 32x32), cols 0..64 (N_rep=2). BK=32 staged tiles, XOR chunk swizzle.
__global__ __launch_bounds__(256) void k_big_mfma(
    const unsigned short* __restrict__ Ah, const unsigned short* __restrict__ Al,
    const unsigned short* __restrict__ ZhT, const unsigned short* __restrict__ ZlT,
    float* __restrict__ P, int kchunk)
{
    __shared__ __align__(16) unsigned short AsH[256 * 32];
    __shared__ __align__(16) unsigned short AsL[256 * 32];
    __shared__ __align__(16) unsigned short ZsH[64 * 32];
    __shared__ __align__(16) unsigned short ZsL[64 * 32];
    const int tid = threadIdx.x;
    const int w = tid >> 6, l = tid & 63;
    const int r0 = blockIdx.x * 256;
    const int k0 = blockIdx.y * kchunk;

    // staging source offsets (ushort units), fixed per lane
    size_t asrc[4];
#pragma unroll
    for (int q = 0; q < 4; ++q) {
        int R = (w * 4 + q) * 16 + (l >> 2);
        int g = SLOTOF(R, l & 3);
        asrc[q] = (size_t)(r0 + R) * N0 + (unsigned)(k0 + g * 8);
    }
    size_t zsrc;
    {
        int C = w * 16 + (l >> 2);
        int g = SLOTOF(C, l & 3);
        zsrc = (size_t)C * N0 + (unsigned)(k0 + g * 8);
    }

    f32x16 acc00, acc01, acc10, acc11;
#pragma unroll
    for (int i = 0; i < 16; ++i) {
        acc00[i] = 0.f; acc01[i] = 0.f; acc10[i] = 0.f; acc11[i] = 0.f;
    }

    const int hi = l >> 5, ln = l & 31;
    const int R0 = w * 64 + ln, R1 = R0 + 32;
    const int C0 = ln, C1 = ln + 32;

    const int ntiles = kchunk / 32;
    for (int t = 0; t < ntiles; ++t) {
        const unsigned kb = (unsigned)(t * 32);
#pragma unroll
        for (int q = 0; q < 4; ++q) {
            __builtin_amdgcn_global_load_lds(
                (const __attribute__((address_space(1))) void*)(Ah + asrc[q] + kb),
                (__attribute__((address_space(3))) void*)(&AsH[(w * 4 + q) * 512]),
                16, 0, 0);
            __builtin_amdgcn_global_load_lds(
                (const __attribute__((address_space(1))) void*)(Al + asrc[q] + kb),
                (__attribute__((address_space(3))) void*)(&AsL[(w * 4 + q) * 512]),
                16, 0, 0);
        }
        __builtin_amdgcn_global_load_lds(
            (const __attribute__((address_space(1))) void*)(ZhT + zsrc + kb),
            (__attribute__((address_space(3))) void*)(&ZsH[w * 512]), 16, 0, 0);
        __builtin_amdgcn_global_load_lds(
            (const __attribute__((address_space(1))) void*)(ZlT + zsrc + kb),
            (__attribute__((address_space(3))) void*)(&ZsL[w * 512]), 16, 0, 0);
        __syncthreads();

#pragma unroll
        for (int s = 0; s < 2; ++s) {
            const int c = s * 2 + hi;
            bf16x8 a0h = *(const bf16x8*)&AsH[R0 * 32 + SLOTOF(R0, c) * 8];
            bf16x8 a1h = *(const bf16x8*)&AsH[R1 * 32 + SLOTOF(R1, c) * 8];
            bf16x8 a0l = *(const bf16x8*)&AsL[R0 * 32 + SLOTOF(R0, c) * 8];
            bf16x8 a1l = *(const bf16x8*)&AsL[R1 * 32 + SLOTOF(R1, c) * 8];
            bf16x8 z0h = *(const bf16x8*)&ZsH[C0 * 32 + SLOTOF(C0, c) * 8];
            bf16x8 z1h = *(const bf16x8*)&ZsH[C1 * 32 + SLOTOF(C1, c) * 8];
            bf16x8 z0l = *(const bf16x8*)&ZsL[C0 * 32 + SLOTOF(C0, c) * 8];
            bf16x8 z1l = *(const bf16x8*)&ZsL[C1 * 32 + SLOTOF(C1, c) * 8];
            acc00 = __builtin_amdgcn_mfma_f32_32x32x16_bf16(a0h, z0h, acc00, 0, 0, 0);
            acc01 = __builtin_amdgcn_mfma_f32_32x32x16_bf16(a0h, z1h, acc01, 0, 0, 0);
            acc10 = __builtin_amdgcn_mfma_f32_32x32x16_bf16(a1h, z0h, acc10, 0, 0, 0);
            acc11 = __builtin_amdgcn_mfma_f32_32x32x16_bf16(a1h, z1h, acc11, 0, 0, 0);
            acc00 = __builtin_amdgcn_mfma_f32_32x32x16_bf16(a0h, z0l, acc00, 0, 0, 0);
            acc01 = __builtin_amdgcn_mfma_f32_32x32x16_bf16(a0h, z1l, acc01, 0, 0, 0);
            acc10 = __builtin_amdgcn_mfma_f32_32x32x16_bf16(a1h, z0l, acc10, 0, 0, 0);
            acc11 = __builtin_amdgcn_mfma_f32_32x32x16_bf16(a1h, z1l, acc11, 0, 0, 0);
            acc00 = __builtin_amdgcn_mfma_f32_32x32x16_bf16(a0l, z0h, acc00, 0, 0, 0);
            acc01 = __builtin_amdgcn_mfma_f32_32x32x16_bf16(a0l, z1h, acc01, 0, 0, 0);
            acc10 = __builtin_amdgcn_mfma_f32_32x32x16_bf16(a1l, z0h, acc10, 0, 0, 0);
            acc11 = __builtin_amdgcn_mfma_f32_32x32x16_bf16(a1l, z1h, acc11, 0, 0, 0);
        }
        __syncthreads();
    }

    // epilogue: C/D layout (m101): row=(r&3)+8*(r>>2)+4*hi, col=ln
    float* Pp = P + (size_t)blockIdx.y * N0 * 64;
#pragma unroll
    for (int r = 0; r < 16; ++r) {
        const int rowb = (r & 3) + 8 * (r >> 2) + 4 * hi;
        const size_t base0 = (size_t)(r0 + w * 64 + rowb) * 64;
        const size_t base1 = (size_t)(r0 + w * 64 + 32 + rowb) * 64;
        Pp[base0 + ln] = acc00[r];
        Pp[base0 + 32 + ln] = acc01[r];
        Pp[base1 + ln] = acc10[r];
        Pp[base1 + 32 + ln] = acc11[r];
    }
}

// ------------------------------------------------------------------- reduce
// Xout[r][c] = bias[c] (+ resid[r][c]) + sum_s P[s][g(r)][c]
__global__ __launch_bounds__(256) void k_reduce(
    const float* __restrict__ P, int splitK, int prows, int rows,
    const int* __restrict__ gidx, const float* __restrict__ bias,
    const float* __restrict__ resid, float* __restrict__ Xout)
{
    int t = blockIdx.x * 256 + threadIdx.x;
    if (t >= rows * 16) return;
    int r = t >> 4, c4 = (t & 15) * 4;
    int g = gidx ? gidx[r] : r;
    float4 s = *(const float4*)(bias + c4);
    if (resid) {
        float4 d = *(const float4*)(resid + (size_t)r * 64 + c4);
        s.x += d.x; s.y += d.y; s.z += d.z; s.w += d.w;
    }
    const float* p = P + (size_t)g * 64 + c4;
    for (int sp = 0; sp < splitK; ++sp) {
        float4 v = *(const float4*)(p + (size_t)sp * prows * 64);
        s.x += v.x; s.y += v.y; s.z += v.z; s.w += v.w;
    }
    *(float4*)(Xout + (size_t)r * 64 + c4) = s;
}

// -------------------------------------------------------------------- score
__global__ __launch_bounds__(256) void k_score(
    const float* __restrict__ X, const float* __restrict__ w,
    const float* __restrict__ bp, float* __restrict__ scores, int n)
{
    __shared__ float ws[64];
    if (threadIdx.x < 64) ws[threadIdx.x] = w[threadIdx.x];
    __syncthreads();
    int r = blockIdx.x * 256 + threadIdx.x;
    if (r >= n) return;
    const float* x = X + (size_t)r * 64;
    float s = 0.f;
#pragma unroll
    for (int k4 = 0; k4 < 16; ++k4) {
        float4 v = *(const float4*)(x + k4 * 4);
        s += v.x * ws[k4 * 4] + v.y * ws[k4 * 4 + 1] +
             v.z * ws[k4 * 4 + 2] + v.w * ws[k4 * 4 + 3];
    }
    s = (s + bp[0]) * 0.01f;
    scores[r] = 1.0f / (1.0f + expf(-s));
}

// --------------------------------------------------------------------- rank
__global__ __launch_bounds__(256) void k_rank(
    const float* __restrict__ scores, int n, int ksel,
    const float* __restrict__ Xin, const int* __restrict__ Iold,
    float* __restrict__ Xp, int* __restrict__ Inew)
{
    extern __shared__ float ss[];
    const int npad = (n + 31) & ~31;
    for (int i = threadIdx.x; i < npad; i += 256)
        ss[i] = (i < n) ? scores[i] : -1.0f;
    __syncthreads();

    const int r = blockIdx.x * 32 + (threadIdx.x >> 3);
    const int p = threadIdx.x & 7;
    const float sr = ss[r];
    const int f4per = npad >> 5;
    int rank = 0;
    for (int f = p * f4per; f < (p + 1) * f4per; ++f) {
        float4 v = *(const float4*)&ss[f * 4];
        int jb = f * 4;
        rank += (v.x > sr) + (v.y > sr) + (v.z > sr) + (v.w > sr);
        rank += (v.x == sr && (jb + 0) < r);
        rank += (v.y == sr && (jb + 1) < r);
        rank += (v.z == sr && (jb + 2) < r);
        rank += (v.w == sr && (jb + 3) < r);
    }
    rank += __shfl_xor(rank, 1);
    rank += __shfl_xor(rank, 2);
    rank += __shfl_xor(rank, 4);

    if (r < n && rank < ksel) {
        if (p == 0) Inew[rank] = Iold ? Iold[r] : r;
        const float* xi = Xin + (size_t)r * 64;
        float* xo = Xp + (size_t)rank * 64;
#pragma unroll
        for (int h = 0; h < 2; ++h) {
            int f = p + h * 8;
            float4 v = *(const float4*)(xi + f * 4);
            v.x *= sr; v.y *= sr; v.z *= sr; v.w *= sr;
            *(float4*)(xo + f * 4) = v;
        }
    }
}

// --------------------------------------------------------------------- host
extern "C" void kernel_launch(void* const* d_in, const int* in_sizes, int n_in,
                              void* d_out, int out_size, void* d_ws,
                              size_t ws_size, hipStream_t stream)
{
    const float* A   = (const float*)d_in[0];
    const float* X0  = (const float*)d_in[1];
    const float* Wst = (const float*)d_in[2];
    const float* bst = (const float*)d_in[3];
    const float* Wdn = (const float*)d_in[4];
    const float* bdn = (const float*)d_in[5];
    const float* Wpl = (const float*)d_in[6];
    const float* bpl = (const float*)d_in[7];
    const float* Wbt = (const float*)d_in[8];
    const float* bbt = (const float*)d_in[9];
    const float* Wup = (const float*)d_in[10];
    const float* bup = (const float*)d_in[11];
    const float* Wen = (const float*)d_in[12];
    const float* ben = (const float*)d_in[13];

    float* out  = (float*)d_out;
    float* OUT2 = out + (size_t)N0 * 64;

    char* ws = (char*)d_ws;
    const size_t XBYTES = (size_t)N0 * 64 * 4;          // 2 MB
    float* Zn = (float*)(ws + 0 * XBYTES);
    float* XA = (float*)(ws + 1 * XBYTES);
    float* XB = (float*)(ws + 2 * XBYTES);
    float* D0 = (float*)(ws + 3 * XBYTES);
    float* D1 = (float*)(ws + 4 * XBYTES);
    float* D2 = (float*)(ws + 5 * XBYTES);
    float* D3 = (float*)(ws + 6 * XBYTES);
    float* scores = (float*)(ws + 7 * XBYTES);
    int* I1 = (int*)(ws + 7 * XBYTES + (size_t)N0 * 4);
    int* I2 = I1 + N0;
    int* I3 = I2 + N0;
    int* I4 = I3 + N0;
    unsigned short* ZhT = (unsigned short*)(ws + 8 * XBYTES);   // 1 MB
    unsigned short* ZlT = ZhT + (size_t)64 * N0;                // 1 MB
    unsigned short* Ah  = (unsigned short*)(ws + 9 * XBYTES);   // 128 MB
    unsigned short* Al  = Ah + (size_t)N0 * N0;                 // 128 MB
    float* P = (float*)(ws + 9 * XBYTES + (size_t)N0 * N0 * 4); // 64 MB (sk=32)

    const int SK = 32, KCH = N0 / SK;   // 256

    // one-time bf16 hi/lo split of A
    k_split_A<<<4096, 256, 0, stream>>>(A, Ah, Al);

    // fp32 layer (start / down0 only; gidx always null at full size)
    auto gcnF = [&](const float* Xin, const float* W1,
                    const float* bias, float* Xout) {
        k_small_gemm<<<N0 / 32, 256, 0, stream>>>(Xin, W1, nullptr, nullptr,
                                                  nullptr, Zn, N0);
        dim3 g(N0 / BM, SK);
        k_big_gemm<<<g, 256, 0, stream>>>(A, Zn, nullptr, P, N0, KCH);
        k_reduce<<<((N0 * 16) + 255) / 256, 256, 0, stream>>>(
            P, SK, N0, N0, nullptr, bias, nullptr, Xout);
    };

    // MFMA layer: no-gather big gemm over all 8192 rows; gather in reduce
    auto gcnM = [&](const float* Xin, int rin, const int* sidx,
                    const float* W1, const float* Xin2, const float* W2,
                    const int* gidx, int rout, const float* bias,
                    const float* resid, float* Xout) {
        if (sidx) hipMemsetAsync(ZhT, 0, (size_t)64 * N0 * 2 * 2, stream);
        k_small_gemm_T<<<(rin + 31) / 32, 256, 0, stream>>>(
            Xin, W1, Xin2, W2, sidx, ZhT, ZlT, rin);
        dim3 g(N0 / 256, SK);
        k_big_mfma<<<g, 256, 0, stream>>>(Ah, Al, ZhT, ZlT, P, KCH);
        k_reduce<<<((rout * 16) + 255) / 256, 256, 0, stream>>>(
            P, SK, N0, rout, gidx, bias, resid, Xout);
    };

    auto poolc = [&](const float* Xlv, int lvl, int n, int ksel,
                     const int* Iold, int* Inew, float* Xp) {
        k_score<<<(n + 255) / 256, 256, 0, stream>>>(Xlv, Wpl + lvl * 64,
                                                     bpl + lvl, scores, n);
        int npad = (n + 31) & ~31;
        k_rank<<<(n + 31) / 32, 256, npad * 4, stream>>>(
            scores, n, ksel, Xlv, Iold, Xp, Inew);
    };

    // sizes: 8192 -> 7372 -> 5160 -> 3096 -> 1548
    gcnF(X0, Wst, bst, OUT2);                       // start (output #2)
    gcnF(OUT2, Wdn + 0 * 4096, bdn + 0 * 64, D0);   // down0 (fp32: level-0 topk)
    poolc(D0, 0, 8192, 7372, nullptr, I1, XA);
    gcnM(XA, 7372, I1, Wdn + 1 * 4096, nullptr, nullptr, I1, 7372,
         bdn + 1 * 64, nullptr, D1);
    poolc(D1, 1, 7372, 5160, I1, I2, XB);
    gcnM(XB, 5160, I2, Wdn + 2 * 4096, nullptr, nullptr, I2, 5160,
         bdn + 2 * 64, nullptr, D2);
    poolc(D2, 2, 5160, 3096, I2, I3, XA);
    gcnM(XA, 3096, I3, Wdn + 3 * 4096, nullptr, nullptr, I3, 3096,
         bdn + 3 * 64, nullptr, D3);
    poolc(D3, 3, 3096, 1548, I3, I4, XB);
    gcnM(XB, 1548, I4, Wbt, nullptr, nullptr, I4, 1548, bbt, nullptr, XA);
    gcnM(XA, 1548, I4, Wup + 0 * 4096, nullptr, nullptr, I3, 3096,
         bup + 0 * 64, D3, XB);
    gcnM(XB, 3096, I3, Wup + 1 * 4096, nullptr, nullptr, I2, 5160,
         bup + 1 * 64, D2, XA);
    gcnM(XA, 5160, I2, Wup + 2 * 4096, nullptr, nullptr, I1, 7372,
         bup + 2 * 64, D1, XB);
    gcnM(XB, 7372, I1, Wup + 3 * 4096, nullptr, nullptr, nullptr, 8192,
         bup + 3 * 64, D0, XA);
    gcnM(XA, 8192, nullptr, Wen, OUT2, Wen + 64 * 64, nullptr, 8192,
         ben, nullptr, out);
}